// Round 1
// 212.708 us; speedup vs baseline: 1.3364x; 1.3364x over previous
//
#include <hip/hip_runtime.h>
#include <hip/hip_bf16.h>
#include <stdint.h>

// ---------------------------------------------------------------------------
// MHA: B=2, S=4096, D=512, H=8, dk=64.
// R10:
//  * flash: 8 waves/block (512 thr), key-split — waves 0-3 take even key
//    groups, waves 4-7 odd; per-wave LDS reads amortize over 32 qrows as
//    before (per-CU LDS/HBM traffic unchanged) while occupancy doubles to
//    4 waves/SIMD. Linear combine (no-max softmax => partial o,l just add)
//    through a small LDS buffer at the end.
//  * proj3/proj_o: m97-style staged GEMM — 128x64 tile, BK=32, double-
//    buffered LDS via global_load_lds(16B), one barrier/iter, both-sides
//    XOR swizzle (q' = quad ^ ((row^(row>>2))&3)) for conflict-free
//    ds_read_b128 fragments. Epilogues (Q scale, K/V fragment reorder)
//    unchanged from R9.
// ---------------------------------------------------------------------------

typedef float  floatx4 __attribute__((ext_vector_type(4)));
typedef __bf16 bf16x8  __attribute__((ext_vector_type(8)));
typedef short  shortx4 __attribute__((ext_vector_type(4)));

#define MFMA16(a, b, c) __builtin_amdgcn_mfma_f32_16x16x32_bf16((a), (b), (c), 0, 0, 0)

// folded into Q projection: (1/sqrt(64)) * log2(e)  -> scores in log2 domain
#define QSCALE 0.1803368801111244f

__device__ __forceinline__ short f2bf(float f) {   // RNE
  union { float f; uint32_t u; } a; a.f = f;
  uint32_t u = a.u;
  u += 0x7fffu + ((u >> 16) & 1u);
  return (short)(u >> 16);
}

// async global->LDS, 16B per lane; lds dest = wave-uniform base + lane*16
__device__ __forceinline__ void stage16(const short* g, short* l) {
  __builtin_amdgcn_global_load_lds(
      (const __attribute__((address_space(1))) void*)g,
      (__attribute__((address_space(3))) void*)l, 16, 0, 0);
}

// ---------------------------------------------------------------------------
// fp32 -> bf16 activations (q,k,v), blockIdx.y picks tensor
// ---------------------------------------------------------------------------
__global__ __launch_bounds__(256) void cvt3_kernel(const float* __restrict__ q,
                                                   const float* __restrict__ k,
                                                   const float* __restrict__ v,
                                                   short* __restrict__ out, int n4) {
  const int which = blockIdx.y;
  const float* in = which == 0 ? q : which == 1 ? k : v;
  short* o = out + (size_t)which * (size_t)n4 * 4;
  int i = blockIdx.x * 256 + threadIdx.x;
  if (i < n4) {
    float4 f = reinterpret_cast<const float4*>(in)[i];
    shortx4 s;
    s.x = f2bf(f.x); s.y = f2bf(f.y); s.z = f2bf(f.z); s.w = f2bf(f.w);
    reinterpret_cast<shortx4*>(o)[i] = s;
  }
}

// weights fp32 -> bf16, blockIdx.y picks tensor
__global__ __launch_bounds__(256) void cvtw_kernel(const float* __restrict__ w0,
                                                   const float* __restrict__ w1,
                                                   const float* __restrict__ w2,
                                                   const float* __restrict__ w3,
                                                   short* __restrict__ out, int n4) {
  const int which = blockIdx.y;
  const float* in = which == 0 ? w0 : which == 1 ? w1 : which == 2 ? w2 : w3;
  short* o = out + (size_t)which * (size_t)n4 * 4;
  int i = blockIdx.x * 256 + threadIdx.x;
  if (i < n4) {
    float4 f = reinterpret_cast<const float4*>(in)[i];
    shortx4 s;
    s.x = f2bf(f.x); s.y = f2bf(f.y); s.z = f2bf(f.z); s.w = f2bf(f.w);
    reinterpret_cast<shortx4*>(o)[i] = s;
  }
}

// ---------------------------------------------------------------------------
// Fused Q/K/V projection. blockIdx.z picks tensor. A[8192,512] x W[512,512]^T.
// 128x64 tile, BK=32, double-buffered LDS (global_load_lds, 1 barrier/iter).
// LDS layout: row-major [rows][32] with k-chunk XOR swizzle:
//   cell(row, q) stored at chunk q ^ ((row ^ (row>>2)) & 3)   (16B chunks)
// Staging threads pre-swizzle the GLOBAL source k-offset so the lane-linear
// LDS dest receives swizzled data; frag ds_read applies the same XOR.
// Wave = 32 rows x 64 cols (2 m-tiles x 4 n-tiles = 8 MFMA / 6 ds_read per kk).
// Epilogues identical to R9 (Q scaled log2-domain; K/V fragment/lane-ordered).
// ---------------------------------------------------------------------------
__global__ __launch_bounds__(256) void proj3_kernel(
    const short* __restrict__ xq, const short* __restrict__ xk, const short* __restrict__ xv,
    const short* __restrict__ wq, const short* __restrict__ wk, const short* __restrict__ wv,
    const float* __restrict__ bq, const float* __restrict__ bk, const float* __restrict__ bv,
    short* __restrict__ Qh, short* __restrict__ KV) {
  const int which = blockIdx.z;
  const short* A = which == 0 ? xq : which == 1 ? xk : xv;
  const short* W = which == 0 ? wq : which == 1 ? wk : wv;
  const float* bias = which == 0 ? bq : which == 1 ? bk : bv;

  __shared__ __align__(16) short sA[2][4096];   // [128][32] swizzled
  __shared__ __align__(16) short sB[2][2048];   // [64][32] swizzled

  const int K = 512;
  const int tid = threadIdx.x;
  const int lane = tid & 63;
  const int wave = tid >> 6;
  const int l15 = lane & 15;
  const int quad = lane >> 4;
  const int tileM = blockIdx.x * 128;
  const int tileN = blockIdx.y * 64;

  // staging: thread t covers LDS 16B chunk (row = t>>2 [+64], chunk = t&3);
  // source k-chunk pre-swizzled so LDS holds cell(row, (t&3)^fr) at slot t&3.
  const int srow = tid >> 2;                       // 0..63
  const int fr = (srow ^ (srow >> 2)) & 3;         // same for srow+64
  const int sq = ((tid & 3) ^ fr) * 8;
  const short* As0 = A + (size_t)(tileM + srow) * K + sq;        // rows 0..63
  const short* As1 = As0 + (size_t)64 * K;                       // rows 64..127
  const short* Bs  = W + (size_t)(tileN + srow) * K + sq;
  const int ldw = wave * 512;                      // wave-uniform LDS slice (shorts)

  // fragment reads: row = (wave*32 + mt*16 + l15); swizzled chunk = quad ^ f(l15)
  const int fl = (l15 ^ (l15 >> 2)) & 3;
  const int qsw = (quad ^ fl) * 8;
  const int ra0 = (wave * 32 + l15) * 32 + qsw;    // A frag mt=0
  const int ra1 = ra0 + 512;                       // mt=1 (+16 rows)
  const int rb0 = l15 * 32 + qsw;                  // B frag (+ nt*512)

  floatx4 acc[2][4];
#pragma unroll
  for (int mt = 0; mt < 2; ++mt)
#pragma unroll
    for (int nt = 0; nt < 4; ++nt) acc[mt][nt] = (floatx4){0.f, 0.f, 0.f, 0.f};

  // prologue: stage k-slice 0 into buffer 0
  stage16(As0, &sA[0][ldw]);
  stage16(As1, &sA[0][2048 + ldw]);
  stage16(Bs,  &sB[0][ldw]);

#pragma unroll 2
  for (int t = 0; t < 16; ++t) {
    __syncthreads();                 // drains own stage vmcnt + block sync
    if (t != 15) {                   // stage next slice into other buffer
      const int kk = (t + 1) * 32;
      short* a_ld = &sA[(t + 1) & 1][ldw];
      stage16(As0 + kk, a_ld);
      stage16(As1 + kk, a_ld + 2048);
      stage16(Bs + kk, &sB[(t + 1) & 1][ldw]);
    }
    const short* sa = sA[t & 1];
    const short* sb = sB[t & 1];
    bf16x8 a0 = *(const bf16x8*)&sa[ra0];
    bf16x8 a1 = *(const bf16x8*)&sa[ra1];
#pragma unroll
    for (int nt = 0; nt < 4; ++nt) {
      bf16x8 wf = *(const bf16x8*)&sb[rb0 + nt * 512];
      acc[0][nt] = MFMA16(a0, wf, acc[0][nt]);
      acc[1][nt] = MFMA16(a1, wf, acc[1][nt]);
    }
  }

#pragma unroll
  for (int mt = 0; mt < 2; ++mt) {
    const int rowbase = tileM + wave * 32 + mt * 16 + quad * 4;  // C/D row = quad*4+reg
    const int b = rowbase >> 12, s = rowbase & 4095;
    const int g = s >> 5;
    if (which == 0) {
      // Q: [bh][s][64], scaled into log2 domain
#pragma unroll
      for (int nt = 0; nt < 4; ++nt) {
        const int col = tileN + nt * 16 + l15;
        const int h = col >> 6, d = col & 63;
        const float bc = bias[col];
#pragma unroll
        for (int r = 0; r < 4; ++r) {
          const int row = rowbase + r;
          const int ss = row & 4095;
          Qh[(size_t)((b * 8 + h) * 4096 + ss) * 64 + d] = f2bf((acc[mt][nt][r] + bc) * QSCALE);
        }
      }
    } else if (which == 1) {
      // K fragment chunks (lane-ordered: region*512 + quadk*128 + key15*8 + j)
      const int key = s & 31;
      const int t = key >> 4;
      const int l15b = key & 15;                 // +r, stays <16
#pragma unroll
      for (int nt = 0; nt < 4; ++nt) {
        const int col = tileN + nt * 16 + l15;
        const int h = col >> 6, dd = col & 63;
        const int ks = dd >> 5, quadk = (dd >> 3) & 3, jj = dd & 7;
        const float bc = bias[col];
        const size_t base = ((size_t)(b * 8 + h) * 128 + g) * 4096 +
                            (size_t)(t * 2 + ks) * 512 + (size_t)quadk * 128 + jj;
#pragma unroll
        for (int r = 0; r < 4; ++r)
          KV[base + (size_t)(l15b + r) * 8] = f2bf(acc[mt][nt][r] + bc);
      }
    } else {
      // V fragment chunks (lane-ordered: 2048 + dt*512 + quadv*128 + d15*8 + j)
      const int p32 = s & 31;                    // multiple of 4
      const int l0 = ((p32 & 15) >> 2) * 8 + (p32 >> 4) * 4;
      const int quadv = l0 >> 3, jv = l0 & 7;    // jv in {0,4}
#pragma unroll
      for (int nt = 0; nt < 4; ++nt) {
        const int col = tileN + nt * 16 + l15;
        const int h = col >> 6, dd = col & 63;
        const int dt = dd >> 4, l15v = dd & 15;
        const float bc = bias[col];
        shortx4 p;
        p.x = f2bf(acc[mt][nt][0] + bc);
        p.y = f2bf(acc[mt][nt][1] + bc);
        p.z = f2bf(acc[mt][nt][2] + bc);
        p.w = f2bf(acc[mt][nt][3] + bc);
        *(shortx4*)(KV + ((size_t)(b * 8 + h) * 128 + g) * 4096 + 2048 +
                    (size_t)dt * 512 + (size_t)quadv * 128 + (size_t)l15v * 8 + jv) = p;
      }
    }
  }
}

// ---------------------------------------------------------------------------
// Output projection: ctx bf16 [8192,512] x Wo^T + bo -> fp32 out.
// Same staged core as proj3.
// ---------------------------------------------------------------------------
__global__ __launch_bounds__(256) void proj_o_kernel(
    const short* __restrict__ A, const short* __restrict__ W,
    const float* __restrict__ bias, float* __restrict__ out) {
  __shared__ __align__(16) short sA[2][4096];
  __shared__ __align__(16) short sB[2][2048];

  const int K = 512;
  const int tid = threadIdx.x;
  const int lane = tid & 63;
  const int wave = tid >> 6;
  const int l15 = lane & 15;
  const int quad = lane >> 4;
  const int tileM = blockIdx.x * 128;
  const int tileN = blockIdx.y * 64;

  const int srow = tid >> 2;
  const int fr = (srow ^ (srow >> 2)) & 3;
  const int sq = ((tid & 3) ^ fr) * 8;
  const short* As0 = A + (size_t)(tileM + srow) * K + sq;
  const short* As1 = As0 + (size_t)64 * K;
  const short* Bs  = W + (size_t)(tileN + srow) * K + sq;
  const int ldw = wave * 512;

  const int fl = (l15 ^ (l15 >> 2)) & 3;
  const int qsw = (quad ^ fl) * 8;
  const int ra0 = (wave * 32 + l15) * 32 + qsw;
  const int ra1 = ra0 + 512;
  const int rb0 = l15 * 32 + qsw;

  floatx4 acc[2][4];
#pragma unroll
  for (int mt = 0; mt < 2; ++mt)
#pragma unroll
    for (int nt = 0; nt < 4; ++nt) acc[mt][nt] = (floatx4){0.f, 0.f, 0.f, 0.f};

  stage16(As0, &sA[0][ldw]);
  stage16(As1, &sA[0][2048 + ldw]);
  stage16(Bs,  &sB[0][ldw]);

#pragma unroll 2
  for (int t = 0; t < 16; ++t) {
    __syncthreads();
    if (t != 15) {
      const int kk = (t + 1) * 32;
      short* a_ld = &sA[(t + 1) & 1][ldw];
      stage16(As0 + kk, a_ld);
      stage16(As1 + kk, a_ld + 2048);
      stage16(Bs + kk, &sB[(t + 1) & 1][ldw]);
    }
    const short* sa = sA[t & 1];
    const short* sb = sB[t & 1];
    bf16x8 a0 = *(const bf16x8*)&sa[ra0];
    bf16x8 a1 = *(const bf16x8*)&sa[ra1];
#pragma unroll
    for (int nt = 0; nt < 4; ++nt) {
      bf16x8 wf = *(const bf16x8*)&sb[rb0 + nt * 512];
      acc[0][nt] = MFMA16(a0, wf, acc[0][nt]);
      acc[1][nt] = MFMA16(a1, wf, acc[1][nt]);
    }
  }

#pragma unroll
  for (int mt = 0; mt < 2; ++mt) {
    const int rowbase = tileM + wave * 32 + mt * 16 + quad * 4;
#pragma unroll
    for (int nt = 0; nt < 4; ++nt) {
      const int col = tileN + nt * 16 + l15;
      const float bc = bias[col];
#pragma unroll
      for (int r = 0; r < 4; ++r) out[(size_t)(rowbase + r) * 512 + col] = acc[mt][nt][r] + bc;
    }
  }
}

// ---------------------------------------------------------------------------
// Flash attention, key-split across waves. 512 threads = 8 waves.
// Waves 0-3 (half=0) compute even key groups, waves 4-7 (half=1) odd groups;
// wave w and w+4 own the SAME 32 qrows (wq = wave&3) so per-wave LDS reads
// amortize over 32 rows (per-CU LDS traffic unchanged vs R9) while occupancy
// doubles to 4 waves/SIMD. No-max fixed-base softmax => partials combine
// linearly (o_a+o_b, l_a+l_b) through LDS at the end.
// Per iter: ONE __syncthreads; each wave stages 2x16B slices of the next
// 16KB group-pair, then runs one COMPUTE on its half of the current pair.
// ---------------------------------------------------------------------------
__global__ __launch_bounds__(512) void flash_kernel(
    const short* __restrict__ Qh, const short* __restrict__ KV,
    short* __restrict__ ctx) {
  __shared__ __align__(16) short sKV[2][8192];   // 2 pairs x 16 KB
  __shared__ float comb[4][64][34];              // half=1 partials (o:32, l:2)

  const int id = blockIdx.x;          // 0..511
  const int xcd = id & 7;
  const int j = id >> 3;              // 0..63
  const int bh = xcd + ((j >> 5) << 3);
  const int qtile = j & 31;

  const int tid = threadIdx.x;
  const int wave = tid >> 6;          // 0..7
  const int lane = tid & 63;
  const int l15 = lane & 15;
  const int quad = lane >> 4;
  const int wq = wave & 3;            // q-row group within block
  const int half = wave >> 2;         // key half: 0 -> group 2i, 1 -> 2i+1
  const int qrow0 = qtile * 128 + wq * 32;

  // Q B-frags: B[k=d=quad*8+i+32ks][n=qrow=l15]
  bf16x8 qf[2][2];
#pragma unroll
  for (int nt = 0; nt < 2; ++nt) {
    const short* Qb = Qh + (size_t)(bh * 4096 + qrow0 + nt * 16 + l15) * 64 + quad * 8;
    qf[nt][0] = *(const bf16x8*)(Qb);
    qf[nt][1] = *(const bf16x8*)(Qb + 32);
  }

  // ones A-fragment (bf16 1.0 = 0x3F80) for MFMA row-sums
  bf16x8 ones;
  {
    union { short s[8]; bf16x8 v; } u;
#pragma unroll
    for (int i = 0; i < 8; ++i) u.s[i] = (short)0x3F80;
    ones = u.v;
  }

  const short* KVb = KV + (size_t)bh * (128 * 4096);
  const short* sg = KVb + wave * 512 + lane * 8;    // staging src (wave slice)
  const int ldw = wave * 512;                       // wave-uniform LDS dest offset

  const floatx4 FZ = (floatx4){0.f, 0.f, 0.f, 0.f};
  floatx4 o[2][4];
  floatx4 lacc[2];
#pragma unroll
  for (int nt = 0; nt < 2; ++nt) {
    lacc[nt] = FZ;
#pragma unroll
    for (int dt = 0; dt < 4; ++dt) o[nt][dt] = FZ;
  }

  // stage groups 0,1 into pair 0 (8 waves x 2 instrs x 1KB = 16KB)
  stage16(sg, &sKV[0][ldw]);
  stage16(sg + 4096, &sKV[0][ldw + 4096]);

#define COMPUTE(S) do {                                                         \
    bf16x8 ka[2][2], vf[4];                                                     \
    ka[0][0] = *(const bf16x8*)&(S)[av];                                        \
    ka[0][1] = *(const bf16x8*)&(S)[av + 512];                                  \
    ka[1][0] = *(const bf16x8*)&(S)[av + 1024];                                 \
    ka[1][1] = *(const bf16x8*)&(S)[av + 1536];                                 \
    vf[0] = *(const bf16x8*)&(S)[av + 2048];                                    \
    vf[1] = *(const bf16x8*)&(S)[av + 2560];                                    \
    vf[2] = *(const bf16x8*)&(S)[av + 3072];                                    \
    vf[3] = *(const bf16x8*)&(S)[av + 3584];                                    \
    floatx4 st[2][2];                                                           \
    _Pragma("unroll")                                                           \
    for (int nt = 0; nt < 2; ++nt)                                              \
      _Pragma("unroll")                                                         \
      for (int t = 0; t < 2; ++t)                                               \
        st[nt][t] = MFMA16(ka[t][1], qf[nt][1], MFMA16(ka[t][0], qf[nt][0], FZ)); \
    bf16x8 pb[2];                                                               \
    _Pragma("unroll")                                                           \
    for (int nt = 0; nt < 2; ++nt) {                                            \
      float p[8];                                                               \
      _Pragma("unroll")                                                         \
      for (int t = 0; t < 2; ++t)                                               \
        _Pragma("unroll")                                                       \
        for (int r = 0; r < 4; ++r) p[t * 4 + r] = __builtin_amdgcn_exp2f(st[nt][t][r]); \
      union { __hip_bfloat162 h2[4]; bf16x8 v8; } u;                            \
      u.h2[0] = __float22bfloat162_rn(float2{p[0], p[1]});                      \
      u.h2[1] = __float22bfloat162_rn(float2{p[2], p[3]});                      \
      u.h2[2] = __float22bfloat162_rn(float2{p[4], p[5]});                      \
      u.h2[3] = __float22bfloat162_rn(float2{p[6], p[7]});                      \
      pb[nt] = u.v8;                                                            \
    }                                                                           \
    _Pragma("unroll")                                                           \
    for (int nt = 0; nt < 2; ++nt) {                                            \
      lacc[nt] = MFMA16(ones, pb[nt], lacc[nt]);                                \
      _Pragma("unroll")                                                         \
      for (int dt = 0; dt < 4; ++dt)                                            \
        o[nt][dt] = MFMA16(vf[dt], pb[nt], o[nt][dt]);                          \
    }                                                                           \
  } while (0)

  const int av = lane * 8;            // lane-ordered chunk address (conflict-free)

  for (int it = 0; it < 64; ++it) {
    __syncthreads();   // drains this wave's staging (vmcnt) + block-wide sync

    if (it != 63) {    // stage next pair into the other 16KB half
      const short* gs = sg + (size_t)(2 * it + 2) * 4096;
      short* ld = &sKV[(it + 1) & 1][ldw];
      stage16(gs, ld);
      stage16(gs + 4096, ld + 4096);
    }

    const short* S = sKV[it & 1] + (half << 12);  // half 0: group 2it; half 1: 2it+1
    COMPUTE(S);
  }
#undef COMPUTE

  // ---- combine halves: half=1 publishes partials, half=0 finishes ----
  __syncthreads();
  if (half) {
    float* cb = comb[wq][lane];
#pragma unroll
    for (int nt = 0; nt < 2; ++nt) {
#pragma unroll
      for (int dt = 0; dt < 4; ++dt)
#pragma unroll
        for (int r = 0; r < 4; ++r) cb[nt * 16 + dt * 4 + r] = o[nt][dt][r];
      cb[32 + nt] = lacc[nt][0];
    }
  }
  __syncthreads();
  if (!half) {
    const float* cb = comb[wq][lane];
    const int b = bh >> 3, h = bh & 7;
#pragma unroll
    for (int nt = 0; nt < 2; ++nt) {
      const float inv = 1.0f / (lacc[nt][0] + cb[32 + nt]);
      const int row = qrow0 + nt * 16 + l15;
      short* cp = ctx + (size_t)(b * 4096 + row) * 512 + h * 64 + quad * 4;
#pragma unroll
      for (int dt = 0; dt < 4; ++dt) {
        union { __hip_bfloat162 h2[2]; shortx4 s4; } u;
        u.h2[0] = __float22bfloat162_rn(
            float2{(o[nt][dt][0] + cb[nt * 16 + dt * 4 + 0]) * inv,
                   (o[nt][dt][1] + cb[nt * 16 + dt * 4 + 1]) * inv});
        u.h2[1] = __float22bfloat162_rn(
            float2{(o[nt][dt][2] + cb[nt * 16 + dt * 4 + 2]) * inv,
                   (o[nt][dt][3] + cb[nt * 16 + dt * 4 + 3]) * inv});
        *(shortx4*)(cp + dt * 16) = u.s4;
      }
    }
  }
}

// ---------------------------------------------------------------------------
extern "C" void kernel_launch(void* const* d_in, const int* in_sizes, int n_in,
                              void* d_out, int out_size, void* d_ws, size_t ws_size,
                              hipStream_t stream) {
  const float* q  = (const float*)d_in[0];
  const float* k  = (const float*)d_in[1];
  const float* v  = (const float*)d_in[2];
  const float* Wq = (const float*)d_in[3];
  const float* bq = (const float*)d_in[4];
  const float* Wk = (const float*)d_in[5];
  const float* bk = (const float*)d_in[6];
  const float* Wv = (const float*)d_in[7];
  const float* bv = (const float*)d_in[8];
  const float* Wo = (const float*)d_in[9];
  const float* bo = (const float*)d_in[10];

  const int XN = 2 * 4096 * 512;
  const int WN = 512 * 512;

  short* ws  = (short*)d_ws;
  short* xqb = ws;                       // q/k/v bf16 (contiguous for cvt3)
  short* xkb = ws + (size_t)XN;
  short* xvb = ws + (size_t)2 * XN;
  short* wqb = ws + (size_t)3 * XN;      // weights bf16 (contiguous for cvtw)
  short* wkb = wqb + WN;
  short* wvb = wkb + WN;
  short* wob = wvb + WN;
  short* Qh  = wob + WN;
  short* KVf = Qh + (size_t)XN;          // fragment-ordered K+V: 2*XN shorts
  short* ctx = xqb;                      // xq dead after projections

  dim3 cg(XN / 4 / 256, 3);
  cvt3_kernel<<<cg, 256, 0, stream>>>(q, k, v, xqb, XN / 4);
  dim3 wg(WN / 4 / 256, 4);
  cvtw_kernel<<<wg, 256, 0, stream>>>(Wq, Wk, Wv, Wo, wqb, WN / 4);

  dim3 pg(64, 8, 3);
  proj3_kernel<<<pg, 256, 0, stream>>>(xqb, xkb, xvb, wqb, wkb, wvb,
                                       bq, bk, bv, Qh, KVf);

  flash_kernel<<<512, 512, 0, stream>>>(Qh, KVf, ctx);

  dim3 og(64, 8);
  proj_o_kernel<<<og, 256, 0, stream>>>(ctx, wob, bo, (float*)d_out);
}